// Round 21
// baseline (864.265 us; speedup 1.0000x reference)
//
#include <hip/hip_runtime.h>

#define NN   30000
#define NE   480000
#define NR   7
#define NSEG (NN*NR)
#define DH   512
#define DIN  21
#define EPSB 1e-5f
#define KSEG 3584          // 7*512 gathered columns (self handled from hbf)

typedef __attribute__((ext_vector_type(8))) short bf16x8;
typedef __attribute__((ext_vector_type(8))) unsigned short u16x8;
typedef __attribute__((ext_vector_type(4))) float f32x4;
typedef unsigned short ushortT;

static inline size_t align256(size_t x){ return (x + 255) & ~(size_t)255; }

__device__ inline float bf2f(ushortT u){
    unsigned int i = ((unsigned int)u) << 16; float f; __builtin_memcpy(&f, &i, 4); return f;
}
__device__ inline ushortT f2bf(float f){
    unsigned int i; __builtin_memcpy(&i, &f, 4);
    unsigned int r = i + 0x7FFFu + ((i >> 16) & 1u);
    return (ushortT)(r >> 16);
}

__device__ inline void load_lds16(const ushortT* g, ushortT* l){
    __builtin_amdgcn_global_load_lds((const __attribute__((address_space(1))) unsigned int*)g,
                                     (__attribute__((address_space(3))) unsigned int*)l,
                                     16, 0, 0);
}

// ---------------- CSR build (counting sort by seg = dst*7+rel) ----------------

__global__ void hist_k(const int* __restrict__ dst, const int* __restrict__ rel,
                       int* __restrict__ counts){
    int e = blockIdx.x*256 + threadIdx.x;
    if (e < NE) atomicAdd(&counts[dst[e]*NR + rel[e]], 1);
}

__global__ void scan1_k(const int* __restrict__ counts, int* __restrict__ bsum){
    __shared__ int sd[256];
    int t = threadIdx.x;
    int base = blockIdx.x*1024 + t*4;
    int s = 0;
#pragma unroll
    for (int i = 0; i < 4; i++){ int idx = base + i; if (idx < NSEG) s += counts[idx]; }
    sd[t] = s; __syncthreads();
    for (int off = 128; off > 0; off >>= 1){
        if (t < off) sd[t] += sd[t+off];
        __syncthreads();
    }
    if (t == 0) bsum[blockIdx.x] = sd[0];
}

__global__ void scan2_k(int* __restrict__ bsum, int nb, int* __restrict__ seg_start){
    __shared__ int sd[256];
    int t = threadIdx.x;
    int v = (t < nb) ? bsum[t] : 0;
    sd[t] = v; __syncthreads();
    for (int off = 1; off < 256; off <<= 1){
        int x = sd[t];
        if (t >= off) x += sd[t-off];
        __syncthreads();
        sd[t] = x; __syncthreads();
    }
    if (t < nb) bsum[t] = (t == 0) ? 0 : sd[t-1];
    if (t == 0) seg_start[NSEG] = NE;
}

__global__ void scan3_k(const int* __restrict__ counts, const int* __restrict__ bsum,
                        int* __restrict__ seg_start){
    __shared__ int sd[256];
    int t = threadIdx.x;
    int base = blockIdx.x*1024 + t*4;
    int v[4]; int s = 0;
#pragma unroll
    for (int i = 0; i < 4; i++){ int idx = base + i; v[i] = (idx < NSEG) ? counts[idx] : 0; s += v[i]; }
    sd[t] = s; __syncthreads();
    for (int off = 1; off < 256; off <<= 1){
        int x = sd[t];
        if (t >= off) x += sd[t-off];
        __syncthreads();
        sd[t] = x; __syncthreads();
    }
    int excl = sd[t] - s + bsum[blockIdx.x];
#pragma unroll
    for (int i = 0; i < 4; i++){
        int idx = base + i;
        if (idx < NSEG){ seg_start[idx] = excl; excl += v[i]; }
    }
}

__global__ void scatter_k(const int* __restrict__ src, const int* __restrict__ dst,
                          const int* __restrict__ rel, const int* __restrict__ seg_start,
                          int* __restrict__ cursor, int* __restrict__ src_sorted){
    int e = blockIdx.x*256 + threadIdx.x;
    if (e < NE){
        int s = dst[e]*NR + rel[e];
        int pos = seg_start[s] + atomicAdd(&cursor[s], 1);
        src_sorted[pos] = src[e];
    }
}

// ---------------- layer 0: segment sum d=21 → Acat0[*,256] (147 upd | 21 self | pad) --------

__global__ void segsum21b_k(const float* __restrict__ x0,
                            const int* __restrict__ seg_start, const int* __restrict__ src_sorted,
                            ushortT* __restrict__ Acat0){
    int n = blockIdx.x;
    int t = threadIdx.x;   // 64
    ushortT* arow = Acat0 + (long)n*256;
    if (t < DIN){
        int sb = n*NR;
        int e0 = seg_start[sb];
#pragma unroll
        for (int r = 0; r < NR; r++){
            int e1 = seg_start[sb + r + 1];
            float a = 0.f;
            for (int e = e0; e < e1; e++) a += x0[(long)src_sorted[e]*DIN + t];
            e0 = e1;
            arow[r*DIN + t] = f2bf(a);
        }
        arow[7*DIN + t] = f2bf(x0[(long)n*DIN + t]);
    }
    if (t >= 40) arow[168 + (t - 40)] = 0;   // 168..191
    arow[192 + t] = 0;                        // 192..255
}

// ---------------- segsum (layers 1,2): one WAVE per node → Acat[*,3584], grid-stride --------

__device__ inline void segsum_body(const ushortT* __restrict__ hbf,
                                   const int* __restrict__ seg_start,
                                   const int* __restrict__ src_sorted,
                                   ushortT* __restrict__ Acat,
                                   int wid, int c0, int lane){
    const int n = c0 + wid;
    const int co = lane*8;

    int sb[8];
#pragma unroll
    for (int i = 0; i < 8; i++) sb[i] = seg_start[n*NR + i];

    ushortT* arow = Acat + (long)wid*KSEG + co;
#pragma unroll
    for (int r = 0; r < NR; r++){
        float a[8];
#pragma unroll
        for (int j = 0; j < 8; j++) a[j] = 0.f;
        int e = sb[r], e1 = sb[r+1];
        for (; e + 3 < e1; e += 4){
            u16x8 v0 = *reinterpret_cast<const u16x8*>(hbf + (long)src_sorted[e  ]*DH + co);
            u16x8 v1 = *reinterpret_cast<const u16x8*>(hbf + (long)src_sorted[e+1]*DH + co);
            u16x8 v2 = *reinterpret_cast<const u16x8*>(hbf + (long)src_sorted[e+2]*DH + co);
            u16x8 v3 = *reinterpret_cast<const u16x8*>(hbf + (long)src_sorted[e+3]*DH + co);
#pragma unroll
            for (int j = 0; j < 8; j++)
                a[j] += (bf2f((ushortT)v0[j]) + bf2f((ushortT)v1[j]))
                      + (bf2f((ushortT)v2[j]) + bf2f((ushortT)v3[j]));
        }
        for (; e < e1; e++){
            u16x8 v = *reinterpret_cast<const u16x8*>(hbf + (long)src_sorted[e]*DH + co);
#pragma unroll
            for (int j = 0; j < 8; j++) a[j] += bf2f((ushortT)v[j]);
        }
        u16x8 o;
#pragma unroll
        for (int j = 0; j < 8; j++) o[j] = f2bf(a[j]);
        *reinterpret_cast<u16x8*>(arow + r*DH) = o;
    }
}

__global__ __launch_bounds__(256)
void segsum_wave_k(const ushortT* __restrict__ hbf,
                   const int* __restrict__ seg_start, const int* __restrict__ src_sorted,
                   ushortT* __restrict__ Acat, int c0, int cn){
    const int lane = threadIdx.x & 63;
    const int gwave = (blockIdx.x*256 + threadIdx.x) >> 6;
    const int nwaves = (gridDim.x*256) >> 6;
    for (int wid = gwave; wid < cn; wid += nwaves)
        segsum_body(hbf, seg_start, src_sorted, Acat, wid, c0, lane);
}

// ---------------- weight concat + bf16 convert: Wcat[512][Kp] ----------------

__global__ void convw_k(const float* __restrict__ lw, const float* __restrict__ sw,
                        int d, int Kp, ushortT* __restrict__ Wc){
    int i = blockIdx.x*256 + threadIdx.x;
    if (i < DH*Kp){
        int n = i / Kp, k = i % Kp;
        float v;
        if (k < 7*d)      v = lw[(long)n*7*d + k];
        else if (k < 8*d) v = sw[(long)n*d + (k - 7*d)];
        else              v = 0.f;
        Wc[i] = f2bf(v);
    }
}

// ---------------- 256x256 MFMA GEMM, A 3-buf + counted vmcnt + post-barrier ks1 MFMA -------
// 8 waves (2M x 4N of 128x64), BK=64. LDS = A 3-buf (96 KB) + B 2-buf (64 KB) = 160 KB.
// m201 trick: ALL ds_reads of iter j complete before the barrier; the ks1 MFMA consumes
// registers only and runs AFTER the barrier, overlapping iter j+1's ds_reads + staging.
// Region safety: iter j+1 stagers overwrite bbuf(j)&1 / abuf(j)%3 whose reads finished
// pre-barrier; vmcnt(4) pre-barrier guards B(j+1)/A(j+1) landing (A(j+2) stays in flight).

__global__ __launch_bounds__(512)
void gemmY_k(const ushortT* __restrict__ A, int lda, int ntA,
             const ushortT* __restrict__ hbase, int M,
             const ushortT* __restrict__ W, int ldw,
             const float* __restrict__ b1, const float* __restrict__ b2,
             float* __restrict__ C, int ldc, int nt, float* __restrict__ sums){
    __shared__ ushortT As[3*2*128*64];   // 96 KB: [abuf][half][128][64]
    __shared__ ushortT Bs[2*2*128*64];   // 64 KB: [bbuf][half][128][64]
    const int t = threadIdx.x;

    // bijective XCD swizzle; panel = l>>1, col-tile = l&1
    const int nwg = gridDim.x;
    int qq = nwg >> 3, rr = nwg & 7;
    int xcd = blockIdx.x & 7, slot = blockIdx.x >> 3;
    int l = xcd*qq + min(xcd, rr) + slot;
    const int bm = (l >> 1)*256;
    const int bn = (l & 1)*256;

    // staging constants: unit u0=t (rows 0-63 of half), u1=t+512 (rows 64-127)
    const int ur0 = t >> 3, ur1 = (t + 512) >> 3;
    const int sw0 = ((t & 7) ^ (ur0 & 7))*8;
    const int sw1 = ((t & 7) ^ (ur1 & 7))*8;
    const int a00 = min(bm + ur0, M-1),       a01 = min(bm + ur1, M-1);
    const int a10 = min(bm + 128 + ur0, M-1), a11 = min(bm + 128 + ur1, M-1);
    const int b00 = bn + ur0,       b01 = bn + ur1;
    const int b10 = bn + 128 + ur0, b11 = bn + 128 + ur1;

    auto stageA = [&](int kt, int h, int buf){
        ushortT* d = &As[buf*16384 + h*8192];
        int r0 = h ? a10 : a00, r1 = h ? a11 : a01;
        const ushortT* p0;
        const ushortT* p1;
        if (kt < ntA){
            p0 = A + (long)r0*lda + kt*64 + sw0;
            p1 = A + (long)r1*lda + kt*64 + sw1;
        } else {
            int k0 = (kt - ntA)*64;
            p0 = hbase + (long)r0*DH + k0 + sw0;
            p1 = hbase + (long)r1*DH + k0 + sw1;
        }
        load_lds16(p0, d + t*8);
        load_lds16(p1, d + (t + 512)*8);
    };
    auto stageB = [&](int kt, int h, int buf){
        ushortT* d = &Bs[buf*16384 + h*8192];
        int r0 = h ? b10 : b00, r1 = h ? b11 : b01;
        load_lds16(W + (long)r0*ldw + kt*64 + sw0, d + t*8);
        load_lds16(W + (long)r1*ldw + kt*64 + sw1, d + (t + 512)*8);
    };

    // fragment constants (R19-verified)
    const int w = t >> 6, lane = t & 63;
    const int wm = w >> 2, wn = w & 3;          // 2M x 4N, wave tile 128x64
    const int r = lane & 15, hi = lane >> 4;
    const int swzk0 = ((hi)     ^ (r & 7))*8;   // ks=0
    const int swzk1 = ((4 + hi) ^ (r & 7))*8;   // ks=1
    const int aBase = wm*8192 + r*64;                          // + abuf*16384
    const int bBase = (wn >> 1)*8192 + ((wn & 1)*64 + r)*64;   // + bbuf*16384

    f32x4 acc[8][4];
#pragma unroll
    for (int m = 0; m < 8; m++)
#pragma unroll
        for (int n = 0; n < 4; n++) acc[m][n] = (f32x4){0.f,0.f,0.f,0.f};

    // prologue: A(0)->abuf0, B(0)->bbuf0, A(1)->abuf1; keep A(1)'s 4 loads in flight
    stageA(0, 0, 0); stageA(0, 1, 0);
    stageB(0, 0, 0); stageB(0, 1, 0);
    if (nt > 1){ stageA(1, 0, 1); stageA(1, 1, 1); }
    asm volatile("s_waitcnt vmcnt(4)" ::: "memory");
    __builtin_amdgcn_s_barrier();

    for (int j = 0; j < nt; ++j){
        const int aoff = (j % 3)*16384;
        const int boff = (j & 1)*16384;
        const bool haveB = (j + 1 < nt);
        const bool haveA = (j + 2 < nt);

        bf16x8 aK[8], bK[4], aL[8], bL[4];
        // ---- ks0: read, stage next, compute ----
#pragma unroll
        for (int m = 0; m < 8; m++)
            aK[m] = *reinterpret_cast<const bf16x8*>(&As[aoff + aBase + m*1024 + swzk0]);
#pragma unroll
        for (int n = 0; n < 4; n++)
            bK[n] = *reinterpret_cast<const bf16x8*>(&Bs[boff + bBase + n*1024 + swzk0]);
        if (haveB){ stageB(j + 1, 0, (j + 1) & 1); stageB(j + 1, 1, (j + 1) & 1); }
        if (haveA){ stageA(j + 2, 0, (j + 2) % 3); stageA(j + 2, 1, (j + 2) % 3); }
        asm volatile("s_waitcnt lgkmcnt(0)" ::: "memory");
        __builtin_amdgcn_sched_barrier(0);
        __builtin_amdgcn_s_setprio(1);
#pragma unroll
        for (int m = 0; m < 8; m++)
#pragma unroll
            for (int n = 0; n < 4; n++)
                acc[m][n] = __builtin_amdgcn_mfma_f32_16x16x32_bf16(aK[m], bK[n], acc[m][n], 0, 0, 0);
        __builtin_amdgcn_s_setprio(0);
        // ---- ks1: read into regs, finish all LDS reads, barrier, THEN compute ----
#pragma unroll
        for (int m = 0; m < 8; m++)
            aL[m] = *reinterpret_cast<const bf16x8*>(&As[aoff + aBase + m*1024 + swzk1]);
#pragma unroll
        for (int n = 0; n < 4; n++)
            bL[n] = *reinterpret_cast<const bf16x8*>(&Bs[boff + bBase + n*1024 + swzk1]);
        asm volatile("s_waitcnt lgkmcnt(0)" ::: "memory");
        __builtin_amdgcn_sched_barrier(0);
        // guard: B(j+1)/A(j+1) landed; A(j+2)'s 4 loads stay in flight
        if (haveA) asm volatile("s_waitcnt vmcnt(4)" ::: "memory");
        else       asm volatile("s_waitcnt vmcnt(0)" ::: "memory");
        __builtin_amdgcn_s_barrier();
        // ks1 MFMA on registers only — overlaps iter j+1's ds_reads + staging issue
        __builtin_amdgcn_s_setprio(1);
#pragma unroll
        for (int m = 0; m < 8; m++)
#pragma unroll
            for (int n = 0; n < 4; n++)
                acc[m][n] = __builtin_amdgcn_mfma_f32_16x16x32_bf16(aL[m], bL[n], acc[m][n], 0, 0, 0);
        __builtin_amdgcn_s_setprio(0);
    }

    // epilogue: bias + fp32 store + fused column stats
#pragma unroll
    for (int n = 0; n < 4; n++){
        int col = bn + wn*64 + n*16 + r;
        float bb = b1[col] + b2[col];
        float s = 0.f, s2 = 0.f;
#pragma unroll
        for (int m = 0; m < 8; m++){
            int row = bm + wm*128 + m*16 + hi*4;
#pragma unroll
            for (int j2 = 0; j2 < 4; j2++){
                if (row + j2 < M){
                    float v = acc[m][n][j2] + bb;
                    C[(long)(row + j2)*ldc + col] = v;
                    s += v; s2 = fmaf(v, v, s2);
                }
            }
        }
        s  += __shfl_xor(s, 16);  s  += __shfl_xor(s, 32);
        s2 += __shfl_xor(s2, 16); s2 += __shfl_xor(s2, 32);
        if (hi == 0){
            atomicAdd(&sums[col], s);
            atomicAdd(&sums[DH + col], s2);
        }
    }
}

// ---------------- BatchNorm passes (fp32 in d_out) ----------------

__global__ void finalize_k(const float* __restrict__ sums, const float* __restrict__ g,
                           const float* __restrict__ b, float* __restrict__ ac){
    int c = blockIdx.x*256 + threadIdx.x;
    if (c < DH){
        float mu  = sums[c] * (1.f/NN);
        float var = sums[DH + c] * (1.f/NN) - mu*mu;
        var = fmaxf(var, 0.f);
        float a = g[c] * rsqrtf(var + EPSB);
        ac[c]      = a;
        ac[DH + c] = fmaf(-mu, a, b[c]);
    }
}

// read-only: stats of relu(a1*x+c1) — no intermediate write
__global__ void brstats_k(const float* __restrict__ o, int M, const float* __restrict__ ac,
                          float* __restrict__ sums2){
    int col = blockIdx.x*256 + threadIdx.x;
    int r0 = blockIdx.y*128;
    int r1 = min(r0 + 128, M);
    float a = ac[col], c = ac[DH + col];
    float s = 0.f, s2 = 0.f;
    for (int r = r0; r < r1; r++){
        float y = fmaxf(fmaf(a, o[(long)r*(3*DH) + col], c), 0.f);
        s += y; s2 = fmaf(y, y, s2);
    }
    atomicAdd(&sums2[col], s);
    atomicAdd(&sums2[DH + col], s2);
}

// single write pass: h = a2*relu(a1*x+c1)+c2 → o (and hbf when needed)
__global__ void bn2write_k(float* __restrict__ o, const float* __restrict__ ac1,
                           const float* __restrict__ ac2, ushortT* __restrict__ hbf,
                           int writeH){
    long i = (long)blockIdx.x*256 + threadIdx.x;
    if (i < (long)NN*DH){
        int r = (int)(i >> 9);
        int c = (int)(i & 511);
        long idx = (long)r*(3*DH) + c;
        float y = fmaxf(fmaf(ac1[c], o[idx], ac1[DH + c]), 0.f);
        float h = fmaf(ac2[c], y, ac2[DH + c]);
        o[idx] = h;
        if (writeH) hbf[i] = f2bf(h);
    }
}

// ---------------- driver ----------------

extern "C" void kernel_launch(void* const* d_in, const int* in_sizes, int n_in,
                              void* d_out, int out_size, void* d_ws, size_t ws_size,
                              hipStream_t stream){
    const float* x0  = (const float*)d_in[0];
    const int*   src = (const int*)d_in[1];
    const int*   dst = (const int*)d_in[2];
    const int*   rel = (const int*)d_in[3];
    const float* lin_w[3]  = {(const float*)d_in[4],  (const float*)d_in[12], (const float*)d_in[20]};
    const float* self_w[3] = {(const float*)d_in[5],  (const float*)d_in[13], (const float*)d_in[21]};
    const float* lin_b[3]  = {(const float*)d_in[6],  (const float*)d_in[14], (const float*)d_in[22]};
    const float* self_b[3] = {(const float*)d_in[7],  (const float*)d_in[15], (const float*)d_in[23]};
    const float* bn1_g[3]  = {(const float*)d_in[8],  (const float*)d_in[16], (const float*)d_in[24]};
    const float* bn1_b[3]  = {(const float*)d_in[9],  (const float*)d_in[17], (const float*)d_in[25]};
    const float* bn2_g[3]  = {(const float*)d_in[10], (const float*)d_in[18], (const float*)d_in[26]};
    const float* bn2_b[3]  = {(const float*)d_in[11], (const float*)d_in[19], (const float*)d_in[27]};

    char* ws = (char*)d_ws;
    size_t off = 0;
    auto alloc = [&](size_t bytes)->char*{ char* p = ws + off; off = align256(off + bytes); return p; };

    int*     seg_start  = (int*)alloc((size_t)(NSEG+1)*4);
    int*     bsum       = (int*)alloc(1024*4);
    int*     src_sorted = (int*)alloc((size_t)NE*4);
    float*   stats      = (float*)alloc((size_t)8*DH*4);
    float*   sums1 = stats;            float* sums2 = stats + 2*DH;
    float*   ac1   = stats + 4*DH;     float* ac2   = stats + 6*DH;
    ushortT* hbf    = (ushortT*)alloc((size_t)NN*DH*2);
    ushortT* Wcat   = (ushortT*)alloc((size_t)DH*4096*2);

    // Acat takes the remainder. counts/cursor (CSR) and Acat0 (layer 0) are aliased
    // into the Acat region — all dead before the first layer-1 segsum write (stream-serial).
    size_t remain = (ws_size > off) ? (ws_size - off) : 0;
    ushortT* Acat   = (ushortT*)(ws + off);
    int*     counts = (int*)Acat;
    int*     cursor = counts + NSEG;
    ushortT* Acat0  = (ushortT*)align256((size_t)(cursor + NSEG));

    long max_nodes = (long)(remain / ((size_t)KSEG*2));
    int chunk;
    if (max_nodes >= NN) chunk = NN;
    else { chunk = (int)(max_nodes & ~255L); if (chunk < 2560) chunk = 2560; }

    // CSR build (graph is layer-invariant)
    hipMemsetAsync(counts, 0, (size_t)NSEG*4, stream);
    hipMemsetAsync(cursor, 0, (size_t)NSEG*4, stream);
    hist_k<<<(NE+255)/256, 256, 0, stream>>>(dst, rel, counts);
    int nb = (NSEG + 1023)/1024;
    scan1_k<<<nb, 256, 0, stream>>>(counts, bsum);
    scan2_k<<<1, 256, 0, stream>>>(bsum, nb, seg_start);
    scan3_k<<<nb, 256, 0, stream>>>(counts, bsum, seg_start);
    scatter_k<<<(NE+255)/256, 256, 0, stream>>>(src, dst, rel, seg_start, cursor, src_sorted);

    float* dout = (float*)d_out;

    for (int layer = 0; layer < 3; layer++){
        int d  = (layer == 0) ? DIN : DH;
        int Kp = (layer == 0) ? 256 : 4096;
        convw_k<<<(DH*Kp + 255)/256, 256, 0, stream>>>(lin_w[layer], self_w[layer], d, Kp, Wcat);
        hipMemsetAsync(stats, 0, (size_t)4*DH*4, stream);   // sums1 + sums2

        if (layer == 0){
            segsum21b_k<<<NN, 64, 0, stream>>>(x0, seg_start, src_sorted, Acat0);
            gemmY_k<<<((NN + 255)/256)*2, 512, 0, stream>>>(
                Acat0, 256, 4, Acat0, NN, Wcat, 256,
                lin_b[layer], self_b[layer],
                dout + layer*DH, 3*DH, 4, sums1);
        } else {
            for (int c0 = 0; c0 < NN; c0 += chunk){
                int cn = (NN - c0 < chunk) ? (NN - c0) : chunk;
                int sgrid = (cn + 3)/4; if (sgrid > 2048) sgrid = 2048;
                segsum_wave_k<<<sgrid, 256, 0, stream>>>(
                    hbf, seg_start, src_sorted, Acat, c0, cn);
                gemmY_k<<<((cn + 255)/256)*2, 512, 0, stream>>>(
                    Acat, KSEG, 56, hbf + (long)c0*DH, cn, Wcat, 4096,
                    lin_b[layer], self_b[layer],
                    dout + (long)c0*(3*DH) + layer*DH, 3*DH, 64, sums1);
            }
        }

        finalize_k<<<2, 256, 0, stream>>>(sums1, bn1_g[layer], bn1_b[layer], ac1);
        brstats_k<<<dim3(2, (NN+127)/128), 256, 0, stream>>>(dout + layer*DH, NN, ac1, sums2);
        finalize_k<<<2, 256, 0, stream>>>(sums2, bn2_g[layer], bn2_b[layer], ac2);
        bn2write_k<<<((long)NN*DH + 255)/256, 256, 0, stream>>>(
            dout + layer*DH, ac1, ac2, hbf, (layer < 2) ? 1 : 0);
    }
}

// Round 22
// 844.905 us; speedup vs baseline: 1.0229x; 1.0229x over previous
//
#include <hip/hip_runtime.h>

#define NN   30000
#define NE   480000
#define NR   7
#define NSEG (NN*NR)
#define DH   512
#define DIN  21
#define EPSB 1e-5f
#define KSEG 3584          // 7*512 gathered columns (self handled from hbf)

typedef __attribute__((ext_vector_type(8))) short bf16x8;
typedef __attribute__((ext_vector_type(8))) unsigned short u16x8;
typedef __attribute__((ext_vector_type(4))) float f32x4;
typedef unsigned short ushortT;

static inline size_t align256(size_t x){ return (x + 255) & ~(size_t)255; }

__device__ inline float bf2f(ushortT u){
    unsigned int i = ((unsigned int)u) << 16; float f; __builtin_memcpy(&f, &i, 4); return f;
}
__device__ inline ushortT f2bf(float f){
    unsigned int i; __builtin_memcpy(&i, &f, 4);
    unsigned int r = i + 0x7FFFu + ((i >> 16) & 1u);
    return (ushortT)(r >> 16);
}

__device__ inline void load_lds16(const ushortT* g, ushortT* l){
    __builtin_amdgcn_global_load_lds((const __attribute__((address_space(1))) unsigned int*)g,
                                     (__attribute__((address_space(3))) unsigned int*)l,
                                     16, 0, 0);
}

// ---------------- CSR build (counting sort by seg = dst*7+rel) ----------------

__global__ void hist_k(const int* __restrict__ dst, const int* __restrict__ rel,
                       int* __restrict__ counts){
    int e = blockIdx.x*256 + threadIdx.x;
    if (e < NE) atomicAdd(&counts[dst[e]*NR + rel[e]], 1);
}

__global__ void scan1_k(const int* __restrict__ counts, int* __restrict__ bsum){
    __shared__ int sd[256];
    int t = threadIdx.x;
    int base = blockIdx.x*1024 + t*4;
    int s = 0;
#pragma unroll
    for (int i = 0; i < 4; i++){ int idx = base + i; if (idx < NSEG) s += counts[idx]; }
    sd[t] = s; __syncthreads();
    for (int off = 128; off > 0; off >>= 1){
        if (t < off) sd[t] += sd[t+off];
        __syncthreads();
    }
    if (t == 0) bsum[blockIdx.x] = sd[0];
}

__global__ void scan2_k(int* __restrict__ bsum, int nb, int* __restrict__ seg_start){
    __shared__ int sd[256];
    int t = threadIdx.x;
    int v = (t < nb) ? bsum[t] : 0;
    sd[t] = v; __syncthreads();
    for (int off = 1; off < 256; off <<= 1){
        int x = sd[t];
        if (t >= off) x += sd[t-off];
        __syncthreads();
        sd[t] = x; __syncthreads();
    }
    if (t < nb) bsum[t] = (t == 0) ? 0 : sd[t-1];
    if (t == 0) seg_start[NSEG] = NE;
}

__global__ void scan3_k(const int* __restrict__ counts, const int* __restrict__ bsum,
                        int* __restrict__ seg_start){
    __shared__ int sd[256];
    int t = threadIdx.x;
    int base = blockIdx.x*1024 + t*4;
    int v[4]; int s = 0;
#pragma unroll
    for (int i = 0; i < 4; i++){ int idx = base + i; v[i] = (idx < NSEG) ? counts[idx] : 0; s += v[i]; }
    sd[t] = s; __syncthreads();
    for (int off = 1; off < 256; off <<= 1){
        int x = sd[t];
        if (t >= off) x += sd[t-off];
        __syncthreads();
        sd[t] = x; __syncthreads();
    }
    int excl = sd[t] - s + bsum[blockIdx.x];
#pragma unroll
    for (int i = 0; i < 4; i++){
        int idx = base + i;
        if (idx < NSEG){ seg_start[idx] = excl; excl += v[i]; }
    }
}

__global__ void scatter_k(const int* __restrict__ src, const int* __restrict__ dst,
                          const int* __restrict__ rel, const int* __restrict__ seg_start,
                          int* __restrict__ cursor, int* __restrict__ src_sorted){
    int e = blockIdx.x*256 + threadIdx.x;
    if (e < NE){
        int s = dst[e]*NR + rel[e];
        int pos = seg_start[s] + atomicAdd(&cursor[s], 1);
        src_sorted[pos] = src[e];
    }
}

// ---------------- layer 0: segment sum d=21 → Acat0[*,256] (147 upd | 21 self | pad) --------

__global__ void segsum21b_k(const float* __restrict__ x0,
                            const int* __restrict__ seg_start, const int* __restrict__ src_sorted,
                            ushortT* __restrict__ Acat0){
    int n = blockIdx.x;
    int t = threadIdx.x;   // 64
    ushortT* arow = Acat0 + (long)n*256;
    if (t < DIN){
        int sb = n*NR;
        int e0 = seg_start[sb];
#pragma unroll
        for (int r = 0; r < NR; r++){
            int e1 = seg_start[sb + r + 1];
            float a = 0.f;
            for (int e = e0; e < e1; e++) a += x0[(long)src_sorted[e]*DIN + t];
            e0 = e1;
            arow[r*DIN + t] = f2bf(a);
        }
        arow[7*DIN + t] = f2bf(x0[(long)n*DIN + t]);
    }
    if (t >= 40) arow[168 + (t - 40)] = 0;   // 168..191
    arow[192 + t] = 0;                        // 192..255
}

// ---------------- segsum (layers 1,2): one WAVE per node → Acat[*,3584], grid-stride --------

__device__ inline void segsum_body(const ushortT* __restrict__ hbf,
                                   const int* __restrict__ seg_start,
                                   const int* __restrict__ src_sorted,
                                   ushortT* __restrict__ Acat,
                                   int wid, int c0, int lane){
    const int n = c0 + wid;
    const int co = lane*8;

    int sb[8];
#pragma unroll
    for (int i = 0; i < 8; i++) sb[i] = seg_start[n*NR + i];

    ushortT* arow = Acat + (long)wid*KSEG + co;
#pragma unroll
    for (int r = 0; r < NR; r++){
        float a[8];
#pragma unroll
        for (int j = 0; j < 8; j++) a[j] = 0.f;
        int e = sb[r], e1 = sb[r+1];
        for (; e + 3 < e1; e += 4){
            u16x8 v0 = *reinterpret_cast<const u16x8*>(hbf + (long)src_sorted[e  ]*DH + co);
            u16x8 v1 = *reinterpret_cast<const u16x8*>(hbf + (long)src_sorted[e+1]*DH + co);
            u16x8 v2 = *reinterpret_cast<const u16x8*>(hbf + (long)src_sorted[e+2]*DH + co);
            u16x8 v3 = *reinterpret_cast<const u16x8*>(hbf + (long)src_sorted[e+3]*DH + co);
#pragma unroll
            for (int j = 0; j < 8; j++)
                a[j] += (bf2f((ushortT)v0[j]) + bf2f((ushortT)v1[j]))
                      + (bf2f((ushortT)v2[j]) + bf2f((ushortT)v3[j]));
        }
        for (; e < e1; e++){
            u16x8 v = *reinterpret_cast<const u16x8*>(hbf + (long)src_sorted[e]*DH + co);
#pragma unroll
            for (int j = 0; j < 8; j++) a[j] += bf2f((ushortT)v[j]);
        }
        u16x8 o;
#pragma unroll
        for (int j = 0; j < 8; j++) o[j] = f2bf(a[j]);
        *reinterpret_cast<u16x8*>(arow + r*DH) = o;
    }
}

__global__ __launch_bounds__(256)
void segsum_wave_k(const ushortT* __restrict__ hbf,
                   const int* __restrict__ seg_start, const int* __restrict__ src_sorted,
                   ushortT* __restrict__ Acat, int c0, int cn){
    const int lane = threadIdx.x & 63;
    const int gwave = (blockIdx.x*256 + threadIdx.x) >> 6;
    const int nwaves = (gridDim.x*256) >> 6;
    for (int wid = gwave; wid < cn; wid += nwaves)
        segsum_body(hbf, seg_start, src_sorted, Acat, wid, c0, lane);
}

// ---------------- weight concat + bf16 convert: Wcat[512][Kp]; also zeroes stats ------------

__global__ void convw_k(const float* __restrict__ lw, const float* __restrict__ sw,
                        int d, int Kp, ushortT* __restrict__ Wc, float* __restrict__ stats){
    int i = blockIdx.x*256 + threadIdx.x;
    if (i < 4*DH) stats[i] = 0.f;            // sums1 + sums2 (consumed after this kernel)
    if (i < DH*Kp){
        int n = i / Kp, k = i % Kp;
        float v;
        if (k < 7*d)      v = lw[(long)n*7*d + k];
        else if (k < 8*d) v = sw[(long)n*d + (k - 7*d)];
        else              v = 0.f;
        Wc[i] = f2bf(v);
    }
}

// ---------------- 256x256 MFMA GEMM, A 3-buf + counted vmcnt(4) (R20, measured best) --------
// 8 waves (2M x 4N of 128x64), BK=64. LDS = A 3-buf (96 KB) + B 2-buf (64 KB) = 160 KB.
// Per K-tile j: read ks0 frags, stage B(j+1)+A(j+2) (8 loads), lgkm(0)+32 MFMA, ks1
// half-phase, vmcnt(4) (A(j+2) stays in flight), one barrier. T2 swizzle both sides.
// fp32 C into d_out slice, fused col-stats.

__global__ __launch_bounds__(512)
void gemmY_k(const ushortT* __restrict__ A, int lda, int ntA,
             const ushortT* __restrict__ hbase, int M,
             const ushortT* __restrict__ W, int ldw,
             const float* __restrict__ b1, const float* __restrict__ b2,
             float* __restrict__ C, int ldc, int nt, float* __restrict__ sums){
    __shared__ ushortT As[3*2*128*64];   // 96 KB: [abuf][half][128][64]
    __shared__ ushortT Bs[2*2*128*64];   // 64 KB: [bbuf][half][128][64]
    const int t = threadIdx.x;

    // bijective XCD swizzle; panel = l>>1, col-tile = l&1
    const int nwg = gridDim.x;
    int qq = nwg >> 3, rr = nwg & 7;
    int xcd = blockIdx.x & 7, slot = blockIdx.x >> 3;
    int l = xcd*qq + min(xcd, rr) + slot;
    const int bm = (l >> 1)*256;
    const int bn = (l & 1)*256;

    // staging constants: unit u0=t (rows 0-63 of half), u1=t+512 (rows 64-127)
    const int ur0 = t >> 3, ur1 = (t + 512) >> 3;
    const int sw0 = ((t & 7) ^ (ur0 & 7))*8;
    const int sw1 = ((t & 7) ^ (ur1 & 7))*8;
    const int a00 = min(bm + ur0, M-1),       a01 = min(bm + ur1, M-1);
    const int a10 = min(bm + 128 + ur0, M-1), a11 = min(bm + 128 + ur1, M-1);
    const int b00 = bn + ur0,       b01 = bn + ur1;
    const int b10 = bn + 128 + ur0, b11 = bn + 128 + ur1;

    auto stageA = [&](int kt, int h, int buf){
        ushortT* d = &As[buf*16384 + h*8192];
        int r0 = h ? a10 : a00, r1 = h ? a11 : a01;
        const ushortT* p0;
        const ushortT* p1;
        if (kt < ntA){
            p0 = A + (long)r0*lda + kt*64 + sw0;
            p1 = A + (long)r1*lda + kt*64 + sw1;
        } else {
            int k0 = (kt - ntA)*64;
            p0 = hbase + (long)r0*DH + k0 + sw0;
            p1 = hbase + (long)r1*DH + k0 + sw1;
        }
        load_lds16(p0, d + t*8);
        load_lds16(p1, d + (t + 512)*8);
    };
    auto stageB = [&](int kt, int h, int buf){
        ushortT* d = &Bs[buf*16384 + h*8192];
        int r0 = h ? b10 : b00, r1 = h ? b11 : b01;
        load_lds16(W + (long)r0*ldw + kt*64 + sw0, d + t*8);
        load_lds16(W + (long)r1*ldw + kt*64 + sw1, d + (t + 512)*8);
    };

    // fragment constants (R19-verified)
    const int w = t >> 6, lane = t & 63;
    const int wm = w >> 2, wn = w & 3;          // 2M x 4N, wave tile 128x64
    const int r = lane & 15, hi = lane >> 4;
    const int swzk0 = ((hi)     ^ (r & 7))*8;   // ks=0
    const int swzk1 = ((4 + hi) ^ (r & 7))*8;   // ks=1
    const int aBase = wm*8192 + r*64;                          // + abuf*16384
    const int bBase = (wn >> 1)*8192 + ((wn & 1)*64 + r)*64;   // + bbuf*16384

    f32x4 acc[8][4];
#pragma unroll
    for (int m = 0; m < 8; m++)
#pragma unroll
        for (int n = 0; n < 4; n++) acc[m][n] = (f32x4){0.f,0.f,0.f,0.f};

    // prologue: A(0)->abuf0, B(0)->bbuf0, A(1)->abuf1; keep A(1)'s 4 loads in flight
    stageA(0, 0, 0); stageA(0, 1, 0);
    stageB(0, 0, 0); stageB(0, 1, 0);
    if (nt > 1){ stageA(1, 0, 1); stageA(1, 1, 1); }
    asm volatile("s_waitcnt vmcnt(4)" ::: "memory");
    __builtin_amdgcn_s_barrier();

    for (int j = 0; j < nt; ++j){
        const int aoff = (j % 3)*16384;
        const int boff = (j & 1)*16384;
        const bool haveB = (j + 1 < nt);
        const bool haveA = (j + 2 < nt);

        bf16x8 aK[8], bK[4];
        // ---- ks0 half-phase ----
#pragma unroll
        for (int m = 0; m < 8; m++)
            aK[m] = *reinterpret_cast<const bf16x8*>(&As[aoff + aBase + m*1024 + swzk0]);
#pragma unroll
        for (int n = 0; n < 4; n++)
            bK[n] = *reinterpret_cast<const bf16x8*>(&Bs[boff + bBase + n*1024 + swzk0]);
        if (haveB){ stageB(j + 1, 0, (j + 1) & 1); stageB(j + 1, 1, (j + 1) & 1); }
        if (haveA){ stageA(j + 2, 0, (j + 2) % 3); stageA(j + 2, 1, (j + 2) % 3); }
        asm volatile("s_waitcnt lgkmcnt(0)" ::: "memory");
        __builtin_amdgcn_sched_barrier(0);
        __builtin_amdgcn_s_setprio(1);
#pragma unroll
        for (int m = 0; m < 8; m++)
#pragma unroll
            for (int n = 0; n < 4; n++)
                acc[m][n] = __builtin_amdgcn_mfma_f32_16x16x32_bf16(aK[m], bK[n], acc[m][n], 0, 0, 0);
        __builtin_amdgcn_s_setprio(0);
        // ---- ks1 half-phase ----
#pragma unroll
        for (int m = 0; m < 8; m++)
            aK[m] = *reinterpret_cast<const bf16x8*>(&As[aoff + aBase + m*1024 + swzk1]);
#pragma unroll
        for (int n = 0; n < 4; n++)
            bK[n] = *reinterpret_cast<const bf16x8*>(&Bs[boff + bBase + n*1024 + swzk1]);
        asm volatile("s_waitcnt lgkmcnt(0)" ::: "memory");
        __builtin_amdgcn_sched_barrier(0);
        __builtin_amdgcn_s_setprio(1);
#pragma unroll
        for (int m = 0; m < 8; m++)
#pragma unroll
            for (int n = 0; n < 4; n++)
                acc[m][n] = __builtin_amdgcn_mfma_f32_16x16x32_bf16(aK[m], bK[n], acc[m][n], 0, 0, 0);
        __builtin_amdgcn_s_setprio(0);

        // guard: B(j+1) (and transitively A(j+1)) landed; A(j+2)'s 4 loads stay in flight
        if (haveA) asm volatile("s_waitcnt vmcnt(4)" ::: "memory");
        else       asm volatile("s_waitcnt vmcnt(0)" ::: "memory");
        __builtin_amdgcn_s_barrier();
    }

    // epilogue: bias + fp32 store + fused column stats
#pragma unroll
    for (int n = 0; n < 4; n++){
        int col = bn + wn*64 + n*16 + r;
        float bb = b1[col] + b2[col];
        float s = 0.f, s2 = 0.f;
#pragma unroll
        for (int m = 0; m < 8; m++){
            int row = bm + wm*128 + m*16 + hi*4;
#pragma unroll
            for (int j2 = 0; j2 < 4; j2++){
                if (row + j2 < M){
                    float v = acc[m][n][j2] + bb;
                    C[(long)(row + j2)*ldc + col] = v;
                    s += v; s2 = fmaf(v, v, s2);
                }
            }
        }
        s  += __shfl_xor(s, 16);  s  += __shfl_xor(s, 32);
        s2 += __shfl_xor(s2, 16); s2 += __shfl_xor(s2, 32);
        if (hi == 0){
            atomicAdd(&sums[col], s);
            atomicAdd(&sums[DH + col], s2);
        }
    }
}

// ---------------- BatchNorm passes (fp32 in d_out; scale/shift computed inline) -------------

__device__ inline void bn_ac(const float* sums, const float* g, const float* b, int c,
                             float& a, float& cc){
    float mu  = sums[c] * (1.f/NN);
    float var = sums[DH + c] * (1.f/NN) - mu*mu;
    var = fmaxf(var, 0.f);
    a  = g[c] * rsqrtf(var + EPSB);
    cc = fmaf(-mu, a, b[c]);
}

// read-only: stats of relu(a1*x+c1); a1,c1 computed inline from sums1
__global__ void brstats_k(const float* __restrict__ o, int M,
                          const float* __restrict__ sums1,
                          const float* __restrict__ g1, const float* __restrict__ b1,
                          float* __restrict__ sums2){
    int col = blockIdx.x*256 + threadIdx.x;
    float a, c;
    bn_ac(sums1, g1, b1, col, a, c);
    int r0 = blockIdx.y*128;
    int r1 = min(r0 + 128, M);
    float s = 0.f, s2 = 0.f;
    for (int r = r0; r < r1; r++){
        float y = fmaxf(fmaf(a, o[(long)r*(3*DH) + col], c), 0.f);
        s += y; s2 = fmaf(y, y, s2);
    }
    atomicAdd(&sums2[col], s);
    atomicAdd(&sums2[DH + col], s2);
}

// single write pass: h = a2*relu(a1*x+c1)+c2 → o (and hbf when needed); acs inline
__global__ void bn2write_k(float* __restrict__ o,
                           const float* __restrict__ sums1,
                           const float* __restrict__ g1, const float* __restrict__ b1,
                           const float* __restrict__ sums2,
                           const float* __restrict__ g2, const float* __restrict__ b2,
                           ushortT* __restrict__ hbf, int writeH){
    long i = (long)blockIdx.x*256 + threadIdx.x;
    if (i < (long)NN*DH){
        int r = (int)(i >> 9);
        int c = (int)(i & 511);
        float a1, c1, a2, c2;
        bn_ac(sums1, g1, b1, c, a1, c1);
        bn_ac(sums2, g2, b2, c, a2, c2);
        long idx = (long)r*(3*DH) + c;
        float y = fmaxf(fmaf(a1, o[idx], c1), 0.f);
        float h = fmaf(a2, y, c2);
        o[idx] = h;
        if (writeH) hbf[i] = f2bf(h);
    }
}

// ---------------- driver ----------------

extern "C" void kernel_launch(void* const* d_in, const int* in_sizes, int n_in,
                              void* d_out, int out_size, void* d_ws, size_t ws_size,
                              hipStream_t stream){
    const float* x0  = (const float*)d_in[0];
    const int*   src = (const int*)d_in[1];
    const int*   dst = (const int*)d_in[2];
    const int*   rel = (const int*)d_in[3];
    const float* lin_w[3]  = {(const float*)d_in[4],  (const float*)d_in[12], (const float*)d_in[20]};
    const float* self_w[3] = {(const float*)d_in[5],  (const float*)d_in[13], (const float*)d_in[21]};
    const float* lin_b[3]  = {(const float*)d_in[6],  (const float*)d_in[14], (const float*)d_in[22]};
    const float* self_b[3] = {(const float*)d_in[7],  (const float*)d_in[15], (const float*)d_in[23]};
    const float* bn1_g[3]  = {(const float*)d_in[8],  (const float*)d_in[16], (const float*)d_in[24]};
    const float* bn1_b[3]  = {(const float*)d_in[9],  (const float*)d_in[17], (const float*)d_in[25]};
    const float* bn2_g[3]  = {(const float*)d_in[10], (const float*)d_in[18], (const float*)d_in[26]};
    const float* bn2_b[3]  = {(const float*)d_in[11], (const float*)d_in[19], (const float*)d_in[27]};

    char* ws = (char*)d_ws;
    size_t off = 0;
    auto alloc = [&](size_t bytes)->char*{ char* p = ws + off; off = align256(off + bytes); return p; };

    int*     seg_start  = (int*)alloc((size_t)(NSEG+1)*4);
    int*     bsum       = (int*)alloc(1024*4);
    int*     src_sorted = (int*)alloc((size_t)NE*4);
    float*   stats      = (float*)alloc((size_t)4*DH*4);
    float*   sums1 = stats;            float* sums2 = stats + 2*DH;
    ushortT* hbf    = (ushortT*)alloc((size_t)NN*DH*2);
    ushortT* Wcat   = (ushortT*)alloc((size_t)DH*4096*2);

    // Acat takes the remainder. counts/cursor (CSR) and Acat0 (layer 0) are aliased
    // into the Acat region — all dead before the first layer-1 segsum write (stream-serial).
    size_t remain = (ws_size > off) ? (ws_size - off) : 0;
    ushortT* Acat   = (ushortT*)(ws + off);
    int*     counts = (int*)Acat;
    int*     cursor = counts + NSEG;   // contiguous with counts → single memset
    ushortT* Acat0  = (ushortT*)align256((size_t)(cursor + NSEG));

    long max_nodes = (long)(remain / ((size_t)KSEG*2));
    int chunk;
    if (max_nodes >= NN) chunk = NN;
    else { chunk = (int)(max_nodes & ~255L); if (chunk < 2560) chunk = 2560; }

    // CSR build (graph is layer-invariant)
    hipMemsetAsync(counts, 0, (size_t)2*NSEG*4, stream);   // counts + cursor
    hist_k<<<(NE+255)/256, 256, 0, stream>>>(dst, rel, counts);
    int nb = (NSEG + 1023)/1024;
    scan1_k<<<nb, 256, 0, stream>>>(counts, bsum);
    scan2_k<<<1, 256, 0, stream>>>(bsum, nb, seg_start);
    scan3_k<<<nb, 256, 0, stream>>>(counts, bsum, seg_start);
    scatter_k<<<(NE+255)/256, 256, 0, stream>>>(src, dst, rel, seg_start, cursor, src_sorted);

    float* dout = (float*)d_out;

    for (int layer = 0; layer < 3; layer++){
        int d  = (layer == 0) ? DIN : DH;
        int Kp = (layer == 0) ? 256 : 4096;
        convw_k<<<(DH*Kp + 255)/256, 256, 0, stream>>>(lin_w[layer], self_w[layer], d, Kp,
                                                       Wcat, stats);

        if (layer == 0){
            segsum21b_k<<<NN, 64, 0, stream>>>(x0, seg_start, src_sorted, Acat0);
            gemmY_k<<<((NN + 255)/256)*2, 512, 0, stream>>>(
                Acat0, 256, 4, Acat0, NN, Wcat, 256,
                lin_b[layer], self_b[layer],
                dout + layer*DH, 3*DH, 4, sums1);
        } else {
            for (int c0 = 0; c0 < NN; c0 += chunk){
                int cn = (NN - c0 < chunk) ? (NN - c0) : chunk;
                int sgrid = (cn + 3)/4; if (sgrid > 2048) sgrid = 2048;
                segsum_wave_k<<<sgrid, 256, 0, stream>>>(
                    hbf, seg_start, src_sorted, Acat, c0, cn);
                gemmY_k<<<((cn + 255)/256)*2, 512, 0, stream>>>(
                    Acat, KSEG, 56, hbf + (long)c0*DH, cn, Wcat, 4096,
                    lin_b[layer], self_b[layer],
                    dout + (long)c0*(3*DH) + layer*DH, 3*DH, 64, sums1);
            }
        }

        brstats_k<<<dim3(2, (NN+127)/128), 256, 0, stream>>>(
            dout + layer*DH, NN, sums1, bn1_g[layer], bn1_b[layer], sums2);
        bn2write_k<<<((long)NN*DH + 255)/256, 256, 0, stream>>>(
            dout + layer*DH, sums1, bn1_g[layer], bn1_b[layer],
            sums2, bn2_g[layer], bn2_b[layer], hbf, (layer < 2) ? 1 : 0);
    }
}